// Round 9
// baseline (1895.238 us; speedup 1.0000x reference)
//
#include <hip/hip_runtime.h>

// RSNEncoder R9: gates GEMM with B-operand loaded global->VGPR (inline-asm
// global_load_dwordx4, L1/L2-hot weights) -- removes B from the LDS pipe.
// LDS stages A only (16KB/tile, 4 bufs = 64KB -> 2 blocks/CU). 32 half-tile
// (K=32) phases, fully template-unrolled; strict-order issues + counted
// vmcnt(10/6/0); 1 barrier/tile; sched_barrier(0) after waits (rule #18).
// Mixed GEMM = R6 verbatim.

#define BDIM 32768
#define DDIM 512
#define BD (BDIM * DDIM)

typedef short bf16x8 __attribute__((ext_vector_type(8)));
typedef float f32x4 __attribute__((ext_vector_type(4)));
typedef unsigned short u16x8 __attribute__((ext_vector_type(8)));

#define AS1 __attribute__((address_space(1)))
#define AS3 __attribute__((address_space(3)))

__device__ __forceinline__ unsigned short f2bf(float f) {
  union { float f; unsigned u; } v; v.f = f;
  return (unsigned short)((v.u + 0x7fffu + ((v.u >> 16) & 1u)) >> 16);  // RNE
}
__device__ __forceinline__ float bf2f(unsigned short b) {
  union { unsigned u; float f; } v; v.u = (unsigned)b << 16; return v.f;
}
__device__ __forceinline__ float sigmf(float x) { return 1.0f / (1.0f + __expf(-x)); }
__device__ __forceinline__ float tanhf_(float x) { return 1.0f - 2.0f / (__expf(2.0f * x) + 1.0f); }
__device__ __forceinline__ void bar() { asm volatile("s_barrier" ::: "memory"); }
#define VMCNT(n) asm volatile("s_waitcnt vmcnt(" #n ")" ::: "memory")

template <int N> struct ICt { static constexpr int v = N; };

// ---- fp32 -> bf16 (all of x) ----
__global__ void cvt_bf16_all(const float* __restrict__ in, unsigned short* __restrict__ out) {
  const size_t stride = (size_t)gridDim.x * 256;
  for (size_t i = (size_t)blockIdx.x * 256 + threadIdx.x; i < (size_t)BD; i += stride) {
    const size_t o = i * 8;
    const float4 a = *(const float4*)(in + o);
    const float4 b = *(const float4*)(in + o + 4);
    u16x8 v;
    v[0] = f2bf(a.x); v[1] = f2bf(a.y); v[2] = f2bf(a.z); v[3] = f2bf(a.w);
    v[4] = f2bf(b.x); v[5] = f2bf(b.y); v[6] = f2bf(b.z); v[7] = f2bf(b.w);
    *(u16x8*)(out + o) = v;
  }
}

// ---- weight prep: Wg[1536][1024] = [Wih | Whh]; Wm[512][1024] = [w1 | w2] ----
__global__ void prep_w(const float* __restrict__ wih, const float* __restrict__ whh,
                       const float* __restrict__ w1, const float* __restrict__ w2,
                       unsigned short* __restrict__ Wg, unsigned short* __restrict__ Wm) {
  int i = blockIdx.x * 256 + threadIdx.x;
  if (i < 1536 * 1024) {
    const int j = i >> 10, k = i & 1023;
    Wg[i] = f2bf((k < 512) ? wih[j * 512 + k] : whh[j * 512 + (k - 512)]);
  } else {
    i -= 1536 * 1024;
    const int j = i >> 10, k = i & 1023;
    Wm[i] = f2bf((k < 512) ? w1[j * 512 + k] : w2[j * 512 + (k - 512)]);
  }
}

// ================= gates kernel =================
// Block 128 rows x 64 d (192 gate-cols); 4 waves 2m x 2n; wave 64 x 96.
// A in LDS: 4 bufs x 16KB. B via global->VGPR frags (dbuf by ht parity).
// 32 half-tiles (K=32). acc[fm][ai]: ai 0,1=r  2,3=z  4,5=i_n  6,7=h_n.
__global__ __launch_bounds__(256, 2) void gru_gates(
    const unsigned short* __restrict__ X, const unsigned short* __restrict__ H,
    const unsigned short* __restrict__ Wg, const float* __restrict__ bih,
    const float* __restrict__ bhh, unsigned short* __restrict__ outB) {
  __shared__ char smem[65536];
  const int t = threadIdx.x;
  const int lane = t & 63, wid = t >> 6;
  const int wm = wid >> 1, wn = wid & 1;
  const int xcd = blockIdx.x & 7, ixc = blockIdx.x >> 3;
  const int bm = xcd * 32 + (ixc >> 3);  // 256 m-blocks of 128 rows
  const int bn = ixc & 7;                // 8 d-blocks

  f32x4 acc[4][8];
  const f32x4 z4 = {0.f, 0.f, 0.f, 0.f};
#pragma unroll
  for (int a = 0; a < 4; ++a)
#pragma unroll
    for (int b = 0; b < 8; ++b) acc[a][b] = z4;

  // A staging source offsets (pre-swizzled col slot; rule #21). 4KB per call.
  int asrc[4];
#pragma unroll
  for (int j = 0; j < 4; ++j) {
    const int slot = j * 256 + t;
    const int row = slot >> 3;
    asrc[j] = (bm * 128 + row) * 1024 + (((slot & 7) * 16) ^ ((row & 7) << 4));
  }
  const char* Xc = (const char*)X;
  const char* Hc = (const char*)H;

  // B fragment pointers: lane l holds W[grow + (l&15)][k: (l>>4)*8 ..8]
  const char* pf[6];
  const int blane = (lane & 15) * 2048 + (lane >> 4) * 16;
#pragma unroll
  for (int fn = 0; fn < 6; ++fn) {
    const int grow = (fn >> 1) * 512 + bn * 64 + wn * 32 + (fn & 1) * 16;
    pf[fn] = (const char*)Wg + (size_t)grow * 2048 + blane;
  }

  bf16x8 bq[2][6];  // B frags, dbuf by ht parity (all indices compile-time)

  // ---- prologue: Bf(ht0), Ast(tile0), Ast(tile1); certify Bf0+Ast0 ----
#pragma unroll
  for (int fn = 0; fn < 6; ++fn)
    asm volatile("global_load_dwordx4 %0, %1, off"
                 : "=&v"(bq[0][fn]) : "v"(pf[fn]) : "memory");
#pragma unroll
  for (int j = 0; j < 4; ++j)
    __builtin_amdgcn_global_load_lds((const AS1 void*)(Xc + asrc[j]),
                                     (AS3 void*)(smem + j * 4096 + t * 16), 16, 0, 0);
#pragma unroll
  for (int j = 0; j < 4; ++j)
    __builtin_amdgcn_global_load_lds((const AS1 void*)(Xc + 128 + asrc[j]),
                                     (AS3 void*)(smem + 16384 + j * 4096 + t * 16), 16, 0, 0);
  VMCNT(4);

  const int afr0 = wm * 64 + (lane & 15);
  const int afsw = (afr0 & 7) << 4;  // same for fm steps of 16

  auto ph = [&](auto ic) {
    constexpr int HT = decltype(ic)::v;  // 0..31
    constexpr int TILE = HT >> 1;
    constexpr int KS = HT & 1;
    if constexpr (KS == 0) bar();  // tile boundary: staged A published
    // A-frag ds_reads (4) — compiler handles lgkm before MFMA use
    const char* pa = smem + (TILE & 3) * 16384;
    const int cb = (KS * 64 + (lane >> 4) * 16) ^ afsw;
    bf16x8 af0 = *(const bf16x8*)(pa + (afr0) * 128 + cb);
    bf16x8 af1 = *(const bf16x8*)(pa + (afr0 + 16) * 128 + cb);
    bf16x8 af2 = *(const bf16x8*)(pa + (afr0 + 32) * 128 + cb);
    bf16x8 af3 = *(const bf16x8*)(pa + (afr0 + 48) * 128 + cb);
    // issue next B frags (strict order before Ast; "memory" pins order)
    if constexpr (HT + 1 < 32) {
#pragma unroll
      for (int fn = 0; fn < 6; ++fn)
        asm volatile("global_load_dwordx4 %0, %1, off offset:%2"
                     : "=&v"(bq[(HT + 1) & 1][fn])
                     : "v"(pf[fn]), "i"((HT + 1) * 64) : "memory");
    }
    // issue A stage for tile+2 (odd half only)
    if constexpr (KS == 1 && TILE + 2 <= 15) {
      constexpr int T2 = TILE + 2;
      const char* base = (T2 < 8) ? Xc : Hc;
#pragma unroll
      for (int j = 0; j < 4; ++j)
        __builtin_amdgcn_global_load_lds(
            (const AS1 void*)(base + (T2 & 7) * 128 + asrc[j]),
            (AS3 void*)(smem + (T2 & 3) * 16384 + j * 4096 + t * 16), 16, 0, 0);
    }
    // counted wait: certify Bf(HT) (+Ast(TILE+1) transitively)
    if constexpr (HT <= 28) { VMCNT(10); }
    else if constexpr (HT <= 30) { VMCNT(6); }
    else { VMCNT(0); }
    __builtin_amdgcn_sched_barrier(0);
    __builtin_amdgcn_s_setprio(1);
#pragma unroll
    for (int fn = 0; fn < 6; ++fn) {
      const int ai = (fn < 4) ? fn : (TILE < 8 ? fn : fn + 2);
      acc[0][ai] = __builtin_amdgcn_mfma_f32_16x16x32_bf16(af0, bq[HT & 1][fn], acc[0][ai], 0, 0, 0);
      acc[1][ai] = __builtin_amdgcn_mfma_f32_16x16x32_bf16(af1, bq[HT & 1][fn], acc[1][ai], 0, 0, 0);
      acc[2][ai] = __builtin_amdgcn_mfma_f32_16x16x32_bf16(af2, bq[HT & 1][fn], acc[2][ai], 0, 0, 0);
      acc[3][ai] = __builtin_amdgcn_mfma_f32_16x16x32_bf16(af3, bq[HT & 1][fn], acc[3][ai], 0, 0, 0);
    }
    __builtin_amdgcn_s_setprio(0);
  };

#define PH(n) ph(ICt<n>{});
  PH(0)  PH(1)  PH(2)  PH(3)  PH(4)  PH(5)  PH(6)  PH(7)
  PH(8)  PH(9)  PH(10) PH(11) PH(12) PH(13) PH(14) PH(15)
  PH(16) PH(17) PH(18) PH(19) PH(20) PH(21) PH(22) PH(23)
  PH(24) PH(25) PH(26) PH(27) PH(28) PH(29) PH(30) PH(31)
#undef PH

  // ---- epilogue: gate math (C/D map col=lane&15, row=(lane>>4)*4+j) ----
  const int erow = (lane >> 4) * 4, ecol = lane & 15;
#pragma unroll
  for (int e = 0; e < 2; ++e) {
    const int d = bn * 64 + wn * 32 + e * 16 + ecol;
    const float br = bih[d] + bhh[d];
    const float bz = bih[512 + d] + bhh[512 + d];
    const float bi = bih[1024 + d];
    const float bh = bhh[1024 + d];
#pragma unroll
    for (int fm = 0; fm < 4; ++fm)
#pragma unroll
      for (int j = 0; j < 4; ++j) {
        const int row = bm * 128 + wm * 64 + fm * 16 + erow + j;
        const size_t off = (size_t)row * 512 + d;
        const float rv = sigmf(acc[fm][0 + e][j] + br);
        const float zv = sigmf(acc[fm][2 + e][j] + bz);
        const float nv = tanhf_(acc[fm][4 + e][j] + bi + rv * (acc[fm][6 + e][j] + bh));
        outB[off] = f2bf((1.0f - zv) * nv + zv * bf2f(H[off]));
      }
  }
}

// ================= mixed kernel (R6 verbatim) =================
template <int MH, int NH>
__device__ __forceinline__ void mfmaQ(f32x4 (&acc)[8][4], const bf16x8 (&af)[4][2],
                                      const bf16x8 (&bv)[2][2]) {
  __builtin_amdgcn_s_setprio(1);
#pragma unroll
  for (int fm = 0; fm < 4; ++fm)
#pragma unroll
    for (int fn = 0; fn < 2; ++fn)
#pragma unroll
      for (int ks = 0; ks < 2; ++ks)
        acc[MH * 4 + fm][NH * 2 + fn] = __builtin_amdgcn_mfma_f32_16x16x32_bf16(
            af[fm][ks], bv[fn][ks], acc[MH * 4 + fm][NH * 2 + fn], 0, 0, 0);
  __builtin_amdgcn_s_setprio(0);
}

template <int WF>
__global__ __launch_bounds__(512, 2) void mixed_gemm(
    const unsigned short* __restrict__ Ka, const unsigned short* __restrict__ Kb,
    const unsigned short* __restrict__ Wm,
    unsigned short* __restrict__ outB, float* __restrict__ outF) {
  __shared__ char smem[131072];
  const int t = threadIdx.x;
  const int lane = t & 63, wid = t >> 6;
  const int wm = wid >> 2, wn = wid & 3;
  const int xcd = blockIdx.x & 7, ixc = blockIdx.x >> 3;
  const int bm = xcd * 16 + (ixc >> 1);
  const int bn = ixc & 1;

  f32x4 acc[8][4];
  const f32x4 z4 = {0.f, 0.f, 0.f, 0.f};
#pragma unroll
  for (int a = 0; a < 8; ++a)
#pragma unroll
    for (int b = 0; b < 4; ++b) acc[a][b] = z4;

  const int trow = t >> 3;
  const int tswz = ((t & 7) * 16) ^ ((trow & 7) << 4);
  int asrc[4], bsrc[4];
#pragma unroll
  for (int i = 0; i < 4; ++i) {
    asrc[i] = (bm * 256 + i * 64 + trow) * 1024 + tswz;
    bsrc[i] = (bn * 256 + i * 64 + trow) * 2048 + tswz;
  }
  const char* Kac = (const char*)Ka;
  const char* Kbc = (const char*)Kb;
  const char* Wc = (const char*)Wm;

  auto issA = [&](int kt, int i) {
    const char* base = ((kt < 8) ? Kac : Kbc) + (kt & 7) * 128 + asrc[i];
    __builtin_amdgcn_global_load_lds(
        (const AS1 void*)base,
        (AS3 void*)(smem + (kt & 1) * 65536 + i * 8192 + t * 16), 16, 0, 0);
  };
  auto issB = [&](int kt, int i) {
    const char* base = Wc + kt * 128 + bsrc[i];
    __builtin_amdgcn_global_load_lds(
        (const AS1 void*)base,
        (AS3 void*)(smem + (kt & 1) * 65536 + 32768 + i * 8192 + t * 16), 16, 0, 0);
  };

  bf16x8 af[4][2], bf0[2][2], bf1[2][2];
  auto readAm = [&](const char* pa, int mh) {
#pragma unroll
    for (int fm = 0; fm < 4; ++fm)
#pragma unroll
      for (int ks = 0; ks < 2; ++ks) {
        const int r = mh * 128 + wm * 64 + fm * 16 + (lane & 15);
        const int c = ks * 64 + (lane >> 4) * 16;
        af[fm][ks] = *(const bf16x8*)(pa + r * 128 + (c ^ ((r & 7) << 4)));
      }
  };
  auto readBm = [&](const char* pb, int nh, bf16x8 (&bv)[2][2]) {
#pragma unroll
    for (int fn = 0; fn < 2; ++fn)
#pragma unroll
      for (int ks = 0; ks < 2; ++ks) {
        const int r = nh * 128 + wn * 32 + fn * 16 + (lane & 15);
        const int c = ks * 64 + (lane >> 4) * 16;
        bv[fn][ks] = *(const bf16x8*)(pb + r * 128 + (c ^ ((r & 7) << 4)));
      }
  };

  issA(0, 0); issA(0, 1); issB(0, 0); issB(0, 1);
  issB(0, 2); issB(0, 3); issA(0, 2); issA(0, 3);
  VMCNT(4);
  bar();

  for (int kt = 0; kt < 16; ++kt) {
    const bool last = (kt == 15);
    const char* pa = smem + (kt & 1) * 65536;
    const char* pb = pa + 32768;
    readAm(pa, 0);
    readBm(pb, 0, bf0);
    if (!last) { issA(kt + 1, 0); issA(kt + 1, 1); VMCNT(4); }
    else       { VMCNT(2); }
    bar();
    mfmaQ<0, 0>(acc, af, bf0);
    bar();
    readBm(pb, 1, bf1);
    if (!last) { issB(kt + 1, 0); issB(kt + 1, 1); VMCNT(4); }
    else       { VMCNT(0); }
    bar();
    mfmaQ<0, 1>(acc, af, bf1);
    bar();
    readAm(pa, 1);
    if (!last) { issB(kt + 1, 2); issB(kt + 1, 3); }
    bar();
    mfmaQ<1, 0>(acc, af, bf0);
    bar();
    if (!last) { issA(kt + 1, 2); issA(kt + 1, 3); VMCNT(4); }
    bar();
    mfmaQ<1, 1>(acc, af, bf1);
    bar();
  }

  const int erow = (lane >> 4) * 4, ecol = lane & 15;
#pragma unroll
  for (int mh = 0; mh < 2; ++mh)
#pragma unroll
    for (int fm = 0; fm < 4; ++fm)
#pragma unroll
      for (int nh = 0; nh < 2; ++nh)
#pragma unroll
        for (int fn = 0; fn < 2; ++fn) {
          const int col = bn * 256 + nh * 128 + wn * 32 + fn * 16 + ecol;
#pragma unroll
          for (int j = 0; j < 4; ++j) {
            const int row = bm * 256 + mh * 128 + wm * 64 + fm * 16 + erow + j;
            const size_t off = (size_t)row * 512 + col;
            const float v = acc[mh * 4 + fm][nh * 2 + fn][j];
            if constexpr (WF) outF[off] = v;
            else              outB[off] = f2bf(v);
          }
        }
}

extern "C" void kernel_launch(void* const* d_in, const int* in_sizes, int n_in,
                              void* d_out, int out_size, void* d_ws, size_t ws_size,
                              hipStream_t stream) {
  const float* x   = (const float*)d_in[0];
  const float* wih = (const float*)d_in[1];
  const float* whh = (const float*)d_in[2];
  const float* bih = (const float*)d_in[3];
  const float* bhh = (const float*)d_in[4];
  const float* w1  = (const float*)d_in[5];
  const float* w2  = (const float*)d_in[6];

  char* ws = (char*)d_ws;
  const size_t bd2 = (size_t)BD * 2;
  unsigned short* xall  = (unsigned short*)ws;                  // 8 x 32 MB
  unsigned short* hb[2] = {(unsigned short*)(ws + 8 * bd2),
                           (unsigned short*)(ws + 9 * bd2)};    // 32 MB each
  unsigned short* Wg = (unsigned short*)(ws + 10 * bd2);        // 3 MB
  unsigned short* Wm = Wg + 1536 * 1024;                        // 1 MB

  hipMemsetAsync(hb[0], 0, bd2, stream);  // h0 = 0
  cvt_bf16_all<<<2048, 256, 0, stream>>>(x, xall);
  prep_w<<<8192, 256, 0, stream>>>(wih, whh, w1, w2, Wg, Wm);

  int hp = 0;
  for (int i = 0; i < 8; ++i) {
    const unsigned short* xi = xall + (size_t)i * BD;
    gru_gates<<<2048, 256, 0, stream>>>(xi, hb[hp], Wg, bih, bhh, hb[hp ^ 1]);
    hp ^= 1;
    if (i & 1) {
      const unsigned short* xprev = xall + (size_t)(i - 1) * BD;
      if (i == 7)
        mixed_gemm<1><<<256, 512, 0, stream>>>(hb[hp], xprev, Wm, nullptr, (float*)d_out);
      else
        mixed_gemm<0><<<256, 512, 0, stream>>>(hb[hp], xprev, Wm, hb[hp ^ 1], nullptr);
      if (i != 7) hp ^= 1;
    }
  }
}

// Round 10
// 1194.411 us; speedup vs baseline: 1.5868x; 1.5868x over previous
//
#include <hip/hip_runtime.h>

// RSNEncoder R10: same 8 waves/CU but TWO independent barrier groups:
// BM=128, 256-thr blocks, LDS <= 80KB -> 2 blocks/CU. m97-simple schedule:
// per K-tile {vmcnt(0); bar; stage(t+1); 20 ds_read; 48 MFMA} — cross-block
// TLP provides the read/MFMA overlap that barrier-locked 8-wave blocks lack.

#define BDIM 32768
#define DDIM 512
#define BD (BDIM * DDIM)

typedef short bf16x8 __attribute__((ext_vector_type(8)));
typedef float f32x4 __attribute__((ext_vector_type(4)));
typedef unsigned short u16x8 __attribute__((ext_vector_type(8)));

#define AS1 __attribute__((address_space(1)))
#define AS3 __attribute__((address_space(3)))

__device__ __forceinline__ unsigned short f2bf(float f) {
  union { float f; unsigned u; } v; v.f = f;
  return (unsigned short)((v.u + 0x7fffu + ((v.u >> 16) & 1u)) >> 16);  // RNE
}
__device__ __forceinline__ float bf2f(unsigned short b) {
  union { unsigned u; float f; } v; v.u = (unsigned)b << 16; return v.f;
}
__device__ __forceinline__ float sigmf(float x) { return 1.0f / (1.0f + __expf(-x)); }
__device__ __forceinline__ float tanhf_(float x) { return 1.0f - 2.0f / (__expf(2.0f * x) + 1.0f); }
__device__ __forceinline__ void bar() { asm volatile("s_barrier" ::: "memory"); }
#define VMCNT(n) asm volatile("s_waitcnt vmcnt(" #n ")" ::: "memory")

template <int N> struct ICt { static constexpr int v = N; };

// ---- fp32 -> bf16 (all of x) ----
__global__ void cvt_bf16_all(const float* __restrict__ in, unsigned short* __restrict__ out) {
  const size_t stride = (size_t)gridDim.x * 256;
  for (size_t i = (size_t)blockIdx.x * 256 + threadIdx.x; i < (size_t)BD; i += stride) {
    const size_t o = i * 8;
    const float4 a = *(const float4*)(in + o);
    const float4 b = *(const float4*)(in + o + 4);
    u16x8 v;
    v[0] = f2bf(a.x); v[1] = f2bf(a.y); v[2] = f2bf(a.z); v[3] = f2bf(a.w);
    v[4] = f2bf(b.x); v[5] = f2bf(b.y); v[6] = f2bf(b.z); v[7] = f2bf(b.w);
    *(u16x8*)(out + o) = v;
  }
}

// ---- weight prep: Wg[1536][1024] = [Wih | Whh]; Wm[512][1024] = [w1 | w2] ----
__global__ void prep_w(const float* __restrict__ wih, const float* __restrict__ whh,
                       const float* __restrict__ w1, const float* __restrict__ w2,
                       unsigned short* __restrict__ Wg, unsigned short* __restrict__ Wm) {
  int i = blockIdx.x * 256 + threadIdx.x;
  if (i < 1536 * 1024) {
    const int j = i >> 10, k = i & 1023;
    Wg[i] = f2bf((k < 512) ? wih[j * 512 + k] : whh[j * 512 + (k - 512)]);
  } else {
    i -= 1536 * 1024;
    const int j = i >> 10, k = i & 1023;
    Wm[i] = f2bf((k < 512) ? w1[j * 512 + k] : w2[j * 512 + (k - 512)]);
  }
}

// ================= gates kernel =================
// Block 128 rows x 64 d (192 gate-cols); 4 waves 2m x 2n; wave 64 x 96.
// LDS: 2 bufs x (A 16KB + B 24KB) = 80KB -> 2 blocks/CU.
// acc[fm][ai]: ai 0,1=r  2,3=z  4,5=i_n  6,7=h_n (e = ai&1 col-16-half).
__global__ __launch_bounds__(256, 2) void gru_gates(
    const unsigned short* __restrict__ X, const unsigned short* __restrict__ H,
    const unsigned short* __restrict__ Wg, const float* __restrict__ bih,
    const float* __restrict__ bhh, unsigned short* __restrict__ outB) {
  __shared__ char smem[81920];
  const int t = threadIdx.x;
  const int lane = t & 63, wid = t >> 6;
  const int wm = wid >> 1, wn = wid & 1;
  const int xcd = blockIdx.x & 7, ixc = blockIdx.x >> 3;
  const int bm = xcd * 32 + (ixc >> 3);  // 256 m-blocks of 128 rows
  const int bn = ixc & 7;                // 8 d-blocks

  f32x4 acc[4][8];
  const f32x4 z4 = {0.f, 0.f, 0.f, 0.f};
#pragma unroll
  for (int a = 0; a < 4; ++a)
#pragma unroll
    for (int b = 0; b < 8; ++b) acc[a][b] = z4;

  // staging source offsets (pre-swizzled col slot; rule #21); 4KB per call
  const int trow = t >> 3;
  const int tswz = ((t & 7) * 16) ^ ((trow & 7) << 4);
  int asrc[4], bsrc[6];
#pragma unroll
  for (int i = 0; i < 4; ++i) asrc[i] = (bm * 128 + i * 32 + trow) * 1024 + tswz;
#pragma unroll
  for (int j = 0; j < 6; ++j)
    bsrc[j] = ((j >> 1) * 512 + bn * 64 + (j & 1) * 32 + trow) * 2048 + tswz;

  const char* Xc = (const char*)X;
  const char* Hc = (const char*)H;
  const char* Wc = (const char*)Wg;

  auto stage = [&](int tt) {  // full tile tt -> buf tt&1 (A 4 + B 6 issues)
    const char* Ab = ((tt < 8) ? Xc : Hc) + (tt & 7) * 128;
    const char* Bb = Wc + tt * 128;
    char* dst = smem + (tt & 1) * 40960;
#pragma unroll
    for (int i = 0; i < 4; ++i)
      __builtin_amdgcn_global_load_lds((const AS1 void*)(Ab + asrc[i]),
                                       (AS3 void*)(dst + i * 4096 + t * 16), 16, 0, 0);
#pragma unroll
    for (int j = 0; j < 6; ++j)
      __builtin_amdgcn_global_load_lds((const AS1 void*)(Bb + bsrc[j]),
                                       (AS3 void*)(dst + 16384 + j * 4096 + t * 16), 16, 0, 0);
  };

  const int ar0 = wm * 64 + (lane & 15);
  const int kc0 = (lane >> 4) * 16;

  auto do_tile = [&](int kt, auto nsel) {
    constexpr int NS = decltype(nsel)::v;  // n-gate acc base: 4 (i_n) or 6 (h_n)
    VMCNT(0);  // own stage loads for tile kt arrived
    bar();     // all waves' stages arrived; prior-tile reads retired
    if (kt + 1 < 16) stage(kt + 1);
    const char* pa = smem + (kt & 1) * 40960;
    const char* pb = pa + 16384;
#pragma unroll
    for (int ks = 0; ks < 2; ++ks) {
      bf16x8 av[4], bv[6];
      const int cb = ks * 64 + kc0;
#pragma unroll
      for (int fm = 0; fm < 4; ++fm) {
        const int r = ar0 + fm * 16;
        av[fm] = *(const bf16x8*)(pa + r * 128 + (cb ^ ((r & 7) << 4)));
      }
#pragma unroll
      for (int fn = 0; fn < 6; ++fn) {
        const int r = (fn >> 1) * 64 + wn * 32 + (fn & 1) * 16 + (lane & 15);
        bv[fn] = *(const bf16x8*)(pb + r * 128 + (cb ^ ((r & 7) << 4)));
      }
      __builtin_amdgcn_s_setprio(1);
#pragma unroll
      for (int fn = 0; fn < 6; ++fn) {
        const int ai = (fn < 4) ? fn : NS + (fn - 4);  // compile-time (fn unrolled)
#pragma unroll
        for (int fm = 0; fm < 4; ++fm)
          acc[fm][ai] = __builtin_amdgcn_mfma_f32_16x16x32_bf16(av[fm], bv[fn],
                                                               acc[fm][ai], 0, 0, 0);
      }
      __builtin_amdgcn_s_setprio(0);
    }
  };

  stage(0);
  for (int kt = 0; kt < 8; ++kt) do_tile(kt, ICt<4>{});       // K<512: i_n
  for (int kt = 8; kt < 16; ++kt) do_tile(kt, ICt<6>{});      // K>=512: h_n

  // epilogue: gate math (C/D map col=lane&15, row=(lane>>4)*4+j)
  const int erow = (lane >> 4) * 4, ecol = lane & 15;
#pragma unroll
  for (int e = 0; e < 2; ++e) {
    const int d = bn * 64 + wn * 32 + e * 16 + ecol;
    const float br = bih[d] + bhh[d];
    const float bz = bih[512 + d] + bhh[512 + d];
    const float bi = bih[1024 + d];
    const float bh = bhh[1024 + d];
#pragma unroll
    for (int fm = 0; fm < 4; ++fm)
#pragma unroll
      for (int j = 0; j < 4; ++j) {
        const int row = bm * 128 + wm * 64 + fm * 16 + erow + j;
        const size_t off = (size_t)row * 512 + d;
        const float rv = sigmf(acc[fm][0 + e][j] + br);
        const float zv = sigmf(acc[fm][2 + e][j] + bz);
        const float nv = tanhf_(acc[fm][4 + e][j] + bi + rv * (acc[fm][6 + e][j] + bh));
        outB[off] = f2bf((1.0f - zv) * nv + zv * bf2f(H[off]));
      }
  }
}

// ================= mixed kernel: out = [h | x_prev] @ [w1|w2]^T =================
// Block 128 x 128; 4 waves 2m x 2n; wave 64 x 64. LDS 2 x 32KB = 64KB -> 2/CU.
template <int WF>
__global__ __launch_bounds__(256, 2) void mixed_gemm(
    const unsigned short* __restrict__ Ka, const unsigned short* __restrict__ Kb,
    const unsigned short* __restrict__ Wm,
    unsigned short* __restrict__ outB, float* __restrict__ outF) {
  __shared__ char smem[65536];
  const int t = threadIdx.x;
  const int lane = t & 63, wid = t >> 6;
  const int wm = wid >> 1, wn = wid & 1;
  const int xcd = blockIdx.x & 7, ixc = blockIdx.x >> 3;  // grid 1024
  const int bm = xcd * 32 + (ixc >> 2);  // 256 m-blocks
  const int bn = ixc & 3;                // 4 n-blocks of 128

  f32x4 acc[4][4];
  const f32x4 z4 = {0.f, 0.f, 0.f, 0.f};
#pragma unroll
  for (int a = 0; a < 4; ++a)
#pragma unroll
    for (int b = 0; b < 4; ++b) acc[a][b] = z4;

  const int trow = t >> 3;
  const int tswz = ((t & 7) * 16) ^ ((trow & 7) << 4);
  int asrc[4], bsrc[4];
#pragma unroll
  for (int i = 0; i < 4; ++i) {
    asrc[i] = (bm * 128 + i * 32 + trow) * 1024 + tswz;
    bsrc[i] = (bn * 128 + i * 32 + trow) * 2048 + tswz;
  }
  const char* Kac = (const char*)Ka;
  const char* Kbc = (const char*)Kb;
  const char* Wc = (const char*)Wm;

  auto stage = [&](int tt) {
    const char* Ab = ((tt < 8) ? Kac : Kbc) + (tt & 7) * 128;
    const char* Bb = Wc + tt * 128;
    char* dst = smem + (tt & 1) * 32768;
#pragma unroll
    for (int i = 0; i < 4; ++i)
      __builtin_amdgcn_global_load_lds((const AS1 void*)(Ab + asrc[i]),
                                       (AS3 void*)(dst + i * 4096 + t * 16), 16, 0, 0);
#pragma unroll
    for (int j = 0; j < 4; ++j)
      __builtin_amdgcn_global_load_lds((const AS1 void*)(Bb + bsrc[j]),
                                       (AS3 void*)(dst + 16384 + j * 4096 + t * 16), 16, 0, 0);
  };

  const int ar0 = wm * 64 + (lane & 15);
  const int br0 = wn * 64 + (lane & 15);
  const int kc0 = (lane >> 4) * 16;

  stage(0);
  for (int kt = 0; kt < 16; ++kt) {
    VMCNT(0);
    bar();
    if (kt + 1 < 16) stage(kt + 1);
    const char* pa = smem + (kt & 1) * 32768;
    const char* pb = pa + 16384;
#pragma unroll
    for (int ks = 0; ks < 2; ++ks) {
      bf16x8 av[4], bv[4];
      const int cb = ks * 64 + kc0;
#pragma unroll
      for (int fm = 0; fm < 4; ++fm) {
        const int r = ar0 + fm * 16;
        av[fm] = *(const bf16x8*)(pa + r * 128 + (cb ^ ((r & 7) << 4)));
      }
#pragma unroll
      for (int fn = 0; fn < 4; ++fn) {
        const int r = br0 + fn * 16;
        bv[fn] = *(const bf16x8*)(pb + r * 128 + (cb ^ ((r & 7) << 4)));
      }
      __builtin_amdgcn_s_setprio(1);
#pragma unroll
      for (int fn = 0; fn < 4; ++fn)
#pragma unroll
        for (int fm = 0; fm < 4; ++fm)
          acc[fm][fn] = __builtin_amdgcn_mfma_f32_16x16x32_bf16(av[fm], bv[fn],
                                                               acc[fm][fn], 0, 0, 0);
      __builtin_amdgcn_s_setprio(0);
    }
  }

  const int erow = (lane >> 4) * 4, ecol = lane & 15;
#pragma unroll
  for (int fm = 0; fm < 4; ++fm)
#pragma unroll
    for (int fn = 0; fn < 4; ++fn) {
      const int col = bn * 128 + wn * 64 + fn * 16 + ecol;
#pragma unroll
      for (int j = 0; j < 4; ++j) {
        const int row = bm * 128 + wm * 64 + fm * 16 + erow + j;
        const size_t off = (size_t)row * 512 + col;
        const float v = acc[fm][fn][j];
        if constexpr (WF) outF[off] = v;
        else              outB[off] = f2bf(v);
      }
    }
}

extern "C" void kernel_launch(void* const* d_in, const int* in_sizes, int n_in,
                              void* d_out, int out_size, void* d_ws, size_t ws_size,
                              hipStream_t stream) {
  const float* x   = (const float*)d_in[0];
  const float* wih = (const float*)d_in[1];
  const float* whh = (const float*)d_in[2];
  const float* bih = (const float*)d_in[3];
  const float* bhh = (const float*)d_in[4];
  const float* w1  = (const float*)d_in[5];
  const float* w2  = (const float*)d_in[6];

  char* ws = (char*)d_ws;
  const size_t bd2 = (size_t)BD * 2;
  unsigned short* xall  = (unsigned short*)ws;                  // 8 x 32 MB
  unsigned short* hb[2] = {(unsigned short*)(ws + 8 * bd2),
                           (unsigned short*)(ws + 9 * bd2)};    // 32 MB each
  unsigned short* Wg = (unsigned short*)(ws + 10 * bd2);        // 3 MB
  unsigned short* Wm = Wg + 1536 * 1024;                        // 1 MB

  hipMemsetAsync(hb[0], 0, bd2, stream);  // h0 = 0
  cvt_bf16_all<<<2048, 256, 0, stream>>>(x, xall);
  prep_w<<<8192, 256, 0, stream>>>(wih, whh, w1, w2, Wg, Wm);

  int hp = 0;
  for (int i = 0; i < 8; ++i) {
    const unsigned short* xi = xall + (size_t)i * BD;
    gru_gates<<<2048, 256, 0, stream>>>(xi, hb[hp], Wg, bih, bhh, hb[hp ^ 1]);
    hp ^= 1;
    if (i & 1) {
      const unsigned short* xprev = xall + (size_t)(i - 1) * BD;
      if (i == 7)
        mixed_gemm<1><<<1024, 256, 0, stream>>>(hb[hp], xprev, Wm, nullptr, (float*)d_out);
      else
        mixed_gemm<0><<<1024, 256, 0, stream>>>(hb[hp], xprev, Wm, hb[hp ^ 1], nullptr);
      if (i != 7) hp ^= 1;
    }
  }
}